// Round 1
// baseline (345.032 us; speedup 1.0000x reference)
//
#include <hip/hip_runtime.h>
#include <hip/hip_fp16.h>
#include <stdint.h>

// ---------------------------------------------------------------------------
// RuleModel forward. ST-gumbel gate forward == exact one-hot column selector,
// so each h @ gate is a gather with index argmax_i(w[i,j]+g[i,j]).
// Fast path: argmax_part (no atomics, register double-buffered load pipeline:
// loads of group u+1 issue before compares of group u, keeping 8-16 loads per
// thread in flight continuously) -> reduce_pairs2 (cooperative, coalesced) ->
// forward (4 rows/block, fp16 h).
// Fallback (small ws): memset -> atomic argmax -> convert -> forward.
// ---------------------------------------------------------------------------

struct GatePtrs {
    const float* w[12];
    const float* g[12];
};

__device__ __forceinline__ unsigned int sortkey(float f) {
    unsigned int u = __float_as_uint(f);
    return u ^ ((u & 0x80000000u) ? 0xFFFFFFFFu : 0x80000000u);
}

// ---------------- fast path: phase A ---------------------------------------
// partial layout (u64): per layer base pbs[l]; entry (slot, chunk, col) at
// pbs[l] + (slot*ch[l] + chunk)*dout[l] + col. chunk = 16 rows.
// value = (sortkey(best) << 32) | best_row.
__global__ __launch_bounds__(256) void argmax_part(GatePtrs gp,
                                                   unsigned long long* __restrict__ part) {
    const int dins[3]  = {1026, 3074, 5122};
    const int douts[3] = {1024, 1024, 512};
    const int chs[3]   = {65, 193, 321};
    const int pbs[3]   = {0, 266240, 1056768};
    int gate = blockIdx.z, layer = gate >> 2, slot = gate & 3;
    int din = dins[layer], dout = douts[layer], ch = chs[layer];
    int s4    = dout >> 2;                    // float4s per row
    int cols4 = s4;                           // 256 (L1/L2) or 128 (L3)
    int sub   = threadIdx.x / cols4;          // 0, or 0/1 for L3
    int c4    = threadIdx.x - sub * cols4;
    int chunk = blockIdx.y * (256 / cols4) + sub;
    if (chunk >= ch) return;
    int r0 = chunk * 16;
    int n  = min(16, din - r0);               // 16 or 2 (tail chunk)
    const float4* __restrict__ wp = (const float4*)gp.w[gate] + (size_t)r0 * s4 + c4;
    const float4* __restrict__ gq = (const float4*)gp.g[gate] + (size_t)r0 * s4 + c4;
    float bx = -3.4e38f, by = bx, bz = bx, bw = bx;
    int ix = r0, iy = r0, iz = r0, iw = r0;
    if (n == 16) {
        // Register double-buffer: two 4-row groups. Loads of group u+1 are
        // issued (program order) before the compares of group u, so each
        // compare waits at vmcnt(8) instead of vmcnt(0); per-thread
        // outstanding loads stay at 8-16 for the whole chunk.
        float4 wv[2][4], gv[2][4];
        const size_t rs = (size_t)s4;
        #pragma unroll
        for (int k = 0; k < 4; ++k) {         // prologue: group 0 (rows 0-3)
            wv[0][k] = wp[(size_t)k * rs];
            gv[0][k] = gq[(size_t)k * rs];
        }
        #pragma unroll
        for (int u = 0; u < 4; ++u) {
            const int cur = u & 1, nxt = cur ^ 1;
            if (u < 3) {                      // issue next group first
                #pragma unroll
                for (int k = 0; k < 4; ++k) {
                    wv[nxt][k] = wp[(size_t)((u + 1) * 4 + k) * rs];
                    gv[nxt][k] = gq[(size_t)((u + 1) * 4 + k) * rs];
                }
            }
            #pragma unroll
            for (int k = 0; k < 4; ++k) {     // consume current group
                int i = r0 + u * 4 + k;
                float vx = wv[cur][k].x + gv[cur][k].x;
                float vy = wv[cur][k].y + gv[cur][k].y;
                float vz = wv[cur][k].z + gv[cur][k].z;
                float vw = wv[cur][k].w + gv[cur][k].w;
                if (vx > bx) { bx = vx; ix = i; }   // strict > keeps first row
                if (vy > by) { by = vy; iy = i; }
                if (vz > bz) { bz = vz; iz = i; }
                if (vw > bw) { bw = vw; iw = i; }
            }
        }
    } else {
        for (int m = 0; m < n; ++m) {
            float4 wv = wp[(size_t)m * s4];
            float4 gv = gq[(size_t)m * s4];
            int i = r0 + m;
            float vx = wv.x + gv.x, vy = wv.y + gv.y;
            float vz = wv.z + gv.z, vw = wv.w + gv.w;
            if (vx > bx) { bx = vx; ix = i; }
            if (vy > by) { by = vy; iy = i; }
            if (vz > bz) { bz = vz; iz = i; }
            if (vw > bw) { bw = vw; iw = i; }
        }
    }
    unsigned long long* dst = part + pbs[layer]
                            + ((size_t)(slot * ch + chunk)) * dout + 4 * c4;
    dst[0] = ((unsigned long long)sortkey(bx) << 32) | (unsigned int)ix;
    dst[1] = ((unsigned long long)sortkey(by) << 32) | (unsigned int)iy;
    dst[2] = ((unsigned long long)sortkey(bz) << 32) | (unsigned int)iz;
    dst[3] = ((unsigned long long)sortkey(bw) << 32) | (unsigned int)iw;
}

// ---------------- fast path: phase B (cooperative reduce) -------------------
// 320 blocks x 256 threads: 32 columns x 8 chunk-lanes. Coalesced reads,
// LDS tree over chunk-lanes. pf[2i+e] = input-e slot index of gate-pair i.
__global__ __launch_bounds__(256) void reduce_pairs2(const unsigned long long* __restrict__ part,
                                                     unsigned short* __restrict__ pf) {
    __shared__ unsigned long long red[256];
    int t = threadIdx.x;
    int k = t >> 5, gi = t & 31;
    int C = blockIdx.x * 32;                  // global col-slot base
    int l, s, g0, half, dout, ch, pb;
    if (C < 4096)      { l = 0; s = C >> 10;          g0 = C & 1023;          half = 1024; dout = 1024; ch = 65;  pb = 0; }
    else if (C < 8192) { l = 1; s = (C - 4096) >> 10; g0 = (C - 4096) & 1023; half = 1024; dout = 1024; ch = 193; pb = 266240; }
    else               { l = 2; s = (C - 8192) >> 9;  g0 = (C - 8192) & 511;  half = 512;  dout = 512;  ch = 321; pb = 1056768; }
    int g = g0 + gi;
    const unsigned long long* __restrict__ p = part + pb + (size_t)(s * ch) * dout + g;
    unsigned long long best = 0;
    for (int c = k; c < ch; c += 8) {
        unsigned long long v = p[(size_t)c * dout];
        if ((unsigned int)(v >> 32) > (unsigned int)(best >> 32)) best = v;
    }
    red[t] = best;
    __syncthreads();
    #pragma unroll
    for (int st = 4; st >= 1; st >>= 1) {
        if (k < st) {
            unsigned long long o = red[t + st * 32];
            if ((unsigned int)(o >> 32) > (unsigned int)(best >> 32)) best = o;
            red[t] = best;
        }
        __syncthreads();
    }
    if (k == 0) {
        int type = s >> 1, e = s & 1;
        int j = 2 * (l * 2048 + type * half + g) + e;
        pf[j] = (unsigned short)best;         // low 16 bits = row index (<5122)
    }
}

// ---------------- fallback: atomic argmax + convert -------------------------
__global__ __launch_bounds__(256) void argmax_atomic(GatePtrs gp,
                                                     unsigned long long* __restrict__ packed) {
    const int dins[3]  = {1026, 3074, 5122};
    const int douts[3] = {1024, 1024, 512};
    const int offs[3]  = {0, 4096, 8192};
    int gate = blockIdx.z, layer = gate >> 2;
    int din = dins[layer], dout = douts[layer];
    int c2 = blockIdx.x * 256 + threadIdx.x;
    int r0 = blockIdx.y * 64;
    if (2 * c2 >= dout || r0 >= din) return;
    int r1 = min(r0 + 64, din);
    const float* __restrict__ w = gp.w[gate];
    const float* __restrict__ g = gp.g[gate];
    float bx = -3.4e38f, by = -3.4e38f;
    int rx = r0, ry = r0;
    #pragma unroll 8
    for (int i = r0; i < r1; ++i) {
        float2 wv = *(const float2*)(w + (size_t)i * dout + 2 * c2);
        float2 gv = *(const float2*)(g + (size_t)i * dout + 2 * c2);
        float vx = wv.x + gv.x, vy = wv.y + gv.y;
        if (vx > bx) { bx = vx; rx = i; }
        if (vy > by) { by = vy; ry = i; }
    }
    unsigned long long* dst = packed + offs[layer] + (gate & 3) * dout + 2 * c2;
    atomicMax(dst, ((unsigned long long)sortkey(bx) << 32)
                   | (unsigned long long)(0xFFFFFFFFu - (unsigned int)rx));
    atomicMax(dst + 1, ((unsigned long long)sortkey(by) << 32)
                   | (unsigned long long)(0xFFFFFFFFu - (unsigned int)ry));
}

__global__ __launch_bounds__(256) void convert_fb(const unsigned long long* __restrict__ packed,
                                                  ushort2* __restrict__ pf) {
    int i = blockIdx.x * 256 + threadIdx.x;
    if (i >= 5120) return;
    int l    = (i < 2048) ? 0 : ((i < 4096) ? 1 : 2);
    int half = (l == 2) ? 512 : 1024;
    int r    = i - l * 2048;
    int type = (r >= half) ? 1 : 0;
    int g    = r - type * half;
    int o1   = l * 4096 + 2 * type * half + g;
    int o2   = o1 + half;
    unsigned int i1 = 0xFFFFFFFFu - (unsigned int)(packed[o1] & 0xFFFFFFFFull);
    unsigned int i2 = 0xFFFFFFFFu - (unsigned int)(packed[o2] & 0xFFFFFFFFull);
    pf[i] = make_ushort2((unsigned short)i1, (unsigned short)i2);
}

// ---------------- forward: 4 rows/block, fp16 packed h ----------------------
__device__ __forceinline__ __half2 bc(unsigned int u) { return __builtin_bit_cast(__half2, u); }
__device__ __forceinline__ unsigned int cb(__half2 h) { return __builtin_bit_cast(unsigned int, h); }

__device__ __forceinline__ uint2 gat(const char* hb, unsigned int s) {
    return *(const uint2*)(hb + (s << 3));
}
__device__ __forceinline__ uint2 andg(uint2 a, uint2 b) {
    return make_uint2(cb(__hmul2(bc(a.x), bc(b.x))), cb(__hmul2(bc(a.y), bc(b.y))));
}
__device__ __forceinline__ uint2 org(uint2 a, uint2 b) {
    __half2 one = __float2half2_rn(1.0f);
    __half2 lo = __hsub2(one, __hmul2(__hsub2(one, bc(a.x)), __hsub2(one, bc(b.x))));
    __half2 hi = __hsub2(one, __hmul2(__hsub2(one, bc(a.y)), __hsub2(one, bc(b.y))));
    return make_uint2(cb(lo), cb(hi));
}

__global__ __launch_bounds__(512) void forward_kernel(const float* __restrict__ x,
                                                      const float* __restrict__ lin_w,
                                                      const ushort2* __restrict__ pairs,
                                                      float* __restrict__ out) {
    __shared__ uint2 h[5122];      // slot s = 4 rows of feature s, fp16 packed
    __shared__ float4 red[8];
    const int t  = threadIdx.x;
    const int r0 = blockIdx.x * 4;
    const char* hb = (const char*)h;

    float xa = x[(size_t)(r0 + 0) * 512 + t];
    float xb = x[(size_t)(r0 + 1) * 512 + t];
    float xc = x[(size_t)(r0 + 2) * 512 + t];
    float xd = x[(size_t)(r0 + 3) * 512 + t];
    ushort2 pa0 = pairs[t], pa1 = pairs[512 + t];
    ushort2 po0 = pairs[1024 + t], po1 = pairs[1536 + t];
    h[t]       = make_uint2(cb(__floats2half2_rn(xa, xb)), cb(__floats2half2_rn(xc, xd)));
    h[512 + t] = make_uint2(cb(__floats2half2_rn(1.f - xa, 1.f - xb)),
                            cb(__floats2half2_rn(1.f - xc, 1.f - xd)));
    if (t == 0) {
        unsigned int o = cb(__float2half2_rn(1.0f));
        h[1024] = make_uint2(o, o);
        h[1025] = make_uint2(0u, 0u);
    }
    __syncthreads();

    {
        uint2 a0 = andg(gat(hb, pa0.x), gat(hb, pa0.y));
        uint2 a1 = andg(gat(hb, pa1.x), gat(hb, pa1.y));
        uint2 o0 = org(gat(hb, po0.x), gat(hb, po0.y));
        uint2 o1 = org(gat(hb, po1.x), gat(hb, po1.y));
        h[1026 + t] = a0; h[1538 + t] = a1;
        h[2050 + t] = o0; h[2562 + t] = o1;
    }
    ushort2 qa0 = pairs[2048 + t], qa1 = pairs[2560 + t];
    ushort2 qo0 = pairs[3072 + t], qo1 = pairs[3584 + t];
    __syncthreads();

    {
        uint2 a0 = andg(gat(hb, qa0.x), gat(hb, qa0.y));
        uint2 a1 = andg(gat(hb, qa1.x), gat(hb, qa1.y));
        uint2 o0 = org(gat(hb, qo0.x), gat(hb, qo0.y));
        uint2 o1 = org(gat(hb, qo1.x), gat(hb, qo1.y));
        h[3074 + t] = a0; h[3586 + t] = a1;
        h[4098 + t] = o0; h[4610 + t] = o1;
    }
    ushort2 za = pairs[4096 + t], zo = pairs[4608 + t];
    float wA = lin_w[t], wO = lin_w[512 + t];
    __syncthreads();

    uint2 cg = andg(gat(hb, za.x), gat(hb, za.y));
    uint2 dg = org(gat(hb, zo.x), gat(hb, zo.y));
    float2 cl = __half22float2(bc(cg.x)), ch2 = __half22float2(bc(cg.y));
    float2 dl = __half22float2(bc(dg.x)), dh = __half22float2(bc(dg.y));
    float4 s;
    s.x = wA * cl.x  + wO * dl.x;
    s.y = wA * cl.y  + wO * dl.y;
    s.z = wA * ch2.x + wO * dh.x;
    s.w = wA * ch2.y + wO * dh.y;

    #pragma unroll
    for (int off = 32; off > 0; off >>= 1) {
        s.x += __shfl_down(s.x, off, 64);
        s.y += __shfl_down(s.y, off, 64);
        s.z += __shfl_down(s.z, off, 64);
        s.w += __shfl_down(s.w, off, 64);
    }
    if ((t & 63) == 0) red[t >> 6] = s;
    __syncthreads();
    if (t == 0) {
        float4 tot = red[0];
        #pragma unroll
        for (int i = 1; i < 8; ++i) {
            tot.x += red[i].x; tot.y += red[i].y;
            tot.z += red[i].z; tot.w += red[i].w;
        }
        *(float4*)(out + r0) = tot;
    }
}

extern "C" void kernel_launch(void* const* d_in, const int* in_sizes, int n_in,
                              void* d_out, int out_size, void* d_ws, size_t ws_size,
                              hipStream_t stream) {
    GatePtrs gp;
    for (int l = 0; l < 3; ++l)
        for (int s = 0; s < 4; ++s) {
            gp.w[l * 4 + s] = (const float*)d_in[l * 8 + s];
            gp.g[l * 4 + s] = (const float*)d_in[l * 8 + 4 + s];
        }
    const float* x     = (const float*)d_in[24];
    const float* lin_w = (const float*)d_in[25];
    float* out = (float*)d_out;

    const size_t partBytes = 1714176ull * 8ull;   // 13,713,408
    if (ws_size >= partBytes + 20480) {
        unsigned long long* part = (unsigned long long*)d_ws;
        unsigned short* pf = (unsigned short*)((char*)d_ws + partBytes);
        dim3 ga(1, 193, 12);
        argmax_part<<<ga, 256, 0, stream>>>(gp, part);
        reduce_pairs2<<<320, 256, 0, stream>>>(part, pf);
        forward_kernel<<<8192, 512, 0, stream>>>(x, lin_w, (const ushort2*)pf, out);
    } else {
        unsigned long long* packed = (unsigned long long*)d_ws;
        ushort2* pf = (ushort2*)((char*)d_ws + 10240 * 8);
        hipMemsetAsync(d_ws, 0, 10240 * 8, stream);
        dim3 ga(2, 81, 12);
        argmax_atomic<<<ga, 256, 0, stream>>>(gp, packed);
        convert_fb<<<20, 256, 0, stream>>>(packed, pf);
        forward_kernel<<<8192, 512, 0, stream>>>(x, lin_w, (const ushort2*)pf, out);
    }
}

// Round 2
// 343.522 us; speedup vs baseline: 1.0044x; 1.0044x over previous
//
#include <hip/hip_runtime.h>
#include <hip/hip_fp16.h>
#include <stdint.h>

// ---------------------------------------------------------------------------
// RuleModel forward. ST-gumbel gate forward == exact one-hot column selector,
// so each h @ gate is a gather with index argmax_i(w[i,j]+g[i,j]).
// Fast path: argmax_part (flat exact grid, FULL 16-row register prefetch:
// all 32 float4 loads issued before any compare, pinned by an asm memory
// fence + __launch_bounds__(256,2) so the scheduler can't re-serialize) ->
// reduce_pairs2 (cooperative, coalesced) -> forward (4 rows/block, fp16 h).
// Fallback (small ws): memset -> atomic argmax -> convert -> forward.
// ---------------------------------------------------------------------------

struct GatePtrs {
    const float* w[12];
    const float* g[12];
};

__device__ __forceinline__ unsigned int sortkey(float f) {
    unsigned int u = __float_as_uint(f);
    return u ^ ((u & 0x80000000u) ? 0xFFFFFFFFu : 0x80000000u);
}

// ---------------- fast path: phase A ---------------------------------------
// partial layout (u64): per layer base pbs[l]; entry (slot, chunk, col) at
// pbs[l] + (slot*ch[l] + chunk)*dout[l] + col. chunk = 16 rows.
// value = (sortkey(best) << 32) | best_row.
// Flat grid of exactly-active blocks:
//   L0: blocks [0,260)    = 4 gates x 65 chunks, 256 cols4 each
//   L1: blocks [260,1032) = 4 gates x 193 chunks
//   L2: blocks [1032,1676)= 4 gates x 161 y-slots (2 chunks of 128 cols4)
__global__ __launch_bounds__(256, 2) void argmax_part(GatePtrs gp,
                                                      unsigned long long* __restrict__ part) {
    const int dins[3]  = {1026, 3074, 5122};
    const int chs[3]   = {65, 193, 321};
    const int pbs[3]   = {0, 266240, 1056768};
    int bid = blockIdx.x;
    int layer, slot, chunk, c4, dout;
    if (bid < 260) {
        layer = 0; slot = bid / 65; chunk = bid - slot * 65;
        c4 = threadIdx.x; dout = 1024;
    } else if (bid < 1032) {
        layer = 1; int r = bid - 260; slot = r / 193; chunk = r - slot * 193;
        c4 = threadIdx.x; dout = 1024;
    } else {
        layer = 2; int r = bid - 1032; slot = r / 161; int cb = r - slot * 161;
        int sub = threadIdx.x >> 7; c4 = threadIdx.x & 127; dout = 512;
        chunk = cb * 2 + sub;
        if (chunk >= 321) return;             // odd tail of the pairing
    }
    int gate = layer * 4 + slot;
    int din = dins[layer], ch = chs[layer];
    int s4 = dout >> 2;                       // float4s per row
    int r0 = chunk * 16;
    int n  = min(16, din - r0);               // 16 or 2 (tail chunk)
    const float4* __restrict__ wp = (const float4*)gp.w[gate] + (size_t)r0 * s4 + c4;
    const float4* __restrict__ gq = (const float4*)gp.g[gate] + (size_t)r0 * s4 + c4;
    float bx = -3.4e38f, by = bx, bz = bx, bw = bx;
    int ix = r0, iy = r0, iz = r0, iw = r0;
    if (n == 16) {
        // Full-chunk prefetch: all 32 float4 loads (w/g pairwise) issued
        // before ANY compare. The empty asm with a memory clobber pins the
        // loads above the compare loop so the scheduler cannot sink them
        // back to their uses; compare k then waits at vmcnt(30-2k), never
        // vmcnt(0). Needs ~128 data VGPRs -> __launch_bounds__(256,2).
        float4 wv[16], gv[16];
        const size_t rs = (size_t)s4;
        #pragma unroll
        for (int k = 0; k < 16; ++k) {
            wv[k] = wp[(size_t)k * rs];
            gv[k] = gq[(size_t)k * rs];
        }
        asm volatile("" ::: "memory");
        #pragma unroll
        for (int k = 0; k < 16; ++k) {
            int i = r0 + k;
            float vx = wv[k].x + gv[k].x;
            float vy = wv[k].y + gv[k].y;
            float vz = wv[k].z + gv[k].z;
            float vw = wv[k].w + gv[k].w;
            if (vx > bx) { bx = vx; ix = i; }   // strict > keeps first row
            if (vy > by) { by = vy; iy = i; }
            if (vz > bz) { bz = vz; iz = i; }
            if (vw > bw) { bw = vw; iw = i; }
        }
    } else {
        for (int m = 0; m < n; ++m) {
            float4 wv = wp[(size_t)m * s4];
            float4 gv = gq[(size_t)m * s4];
            int i = r0 + m;
            float vx = wv.x + gv.x, vy = wv.y + gv.y;
            float vz = wv.z + gv.z, vw = wv.w + gv.w;
            if (vx > bx) { bx = vx; ix = i; }
            if (vy > by) { by = vy; iy = i; }
            if (vz > bz) { bz = vz; iz = i; }
            if (vw > bw) { bw = vw; iw = i; }
        }
    }
    unsigned long long* dst = part + pbs[layer]
                            + ((size_t)(slot * ch + chunk)) * dout + 4 * c4;
    dst[0] = ((unsigned long long)sortkey(bx) << 32) | (unsigned int)ix;
    dst[1] = ((unsigned long long)sortkey(by) << 32) | (unsigned int)iy;
    dst[2] = ((unsigned long long)sortkey(bz) << 32) | (unsigned int)iz;
    dst[3] = ((unsigned long long)sortkey(bw) << 32) | (unsigned int)iw;
}

// ---------------- fast path: phase B (cooperative reduce) -------------------
// 320 blocks x 256 threads: 32 columns x 8 chunk-lanes. Coalesced reads,
// LDS tree over chunk-lanes. pf[2i+e] = input-e slot index of gate-pair i.
__global__ __launch_bounds__(256) void reduce_pairs2(const unsigned long long* __restrict__ part,
                                                     unsigned short* __restrict__ pf) {
    __shared__ unsigned long long red[256];
    int t = threadIdx.x;
    int k = t >> 5, gi = t & 31;
    int C = blockIdx.x * 32;                  // global col-slot base
    int l, s, g0, half, dout, ch, pb;
    if (C < 4096)      { l = 0; s = C >> 10;          g0 = C & 1023;          half = 1024; dout = 1024; ch = 65;  pb = 0; }
    else if (C < 8192) { l = 1; s = (C - 4096) >> 10; g0 = (C - 4096) & 1023; half = 1024; dout = 1024; ch = 193; pb = 266240; }
    else               { l = 2; s = (C - 8192) >> 9;  g0 = (C - 8192) & 511;  half = 512;  dout = 512;  ch = 321; pb = 1056768; }
    int g = g0 + gi;
    const unsigned long long* __restrict__ p = part + pb + (size_t)(s * ch) * dout + g;
    unsigned long long best = 0;
    for (int c = k; c < ch; c += 8) {
        unsigned long long v = p[(size_t)c * dout];
        if ((unsigned int)(v >> 32) > (unsigned int)(best >> 32)) best = v;
    }
    red[t] = best;
    __syncthreads();
    #pragma unroll
    for (int st = 4; st >= 1; st >>= 1) {
        if (k < st) {
            unsigned long long o = red[t + st * 32];
            if ((unsigned int)(o >> 32) > (unsigned int)(best >> 32)) best = o;
            red[t] = best;
        }
        __syncthreads();
    }
    if (k == 0) {
        int type = s >> 1, e = s & 1;
        int j = 2 * (l * 2048 + type * half + g) + e;
        pf[j] = (unsigned short)best;         // low 16 bits = row index (<5122)
    }
}

// ---------------- fallback: atomic argmax + convert -------------------------
__global__ __launch_bounds__(256) void argmax_atomic(GatePtrs gp,
                                                     unsigned long long* __restrict__ packed) {
    const int dins[3]  = {1026, 3074, 5122};
    const int douts[3] = {1024, 1024, 512};
    const int offs[3]  = {0, 4096, 8192};
    int gate = blockIdx.z, layer = gate >> 2;
    int din = dins[layer], dout = douts[layer];
    int c2 = blockIdx.x * 256 + threadIdx.x;
    int r0 = blockIdx.y * 64;
    if (2 * c2 >= dout || r0 >= din) return;
    int r1 = min(r0 + 64, din);
    const float* __restrict__ w = gp.w[gate];
    const float* __restrict__ g = gp.g[gate];
    float bx = -3.4e38f, by = -3.4e38f;
    int rx = r0, ry = r0;
    #pragma unroll 8
    for (int i = r0; i < r1; ++i) {
        float2 wv = *(const float2*)(w + (size_t)i * dout + 2 * c2);
        float2 gv = *(const float2*)(g + (size_t)i * dout + 2 * c2);
        float vx = wv.x + gv.x, vy = wv.y + gv.y;
        if (vx > bx) { bx = vx; rx = i; }
        if (vy > by) { by = vy; ry = i; }
    }
    unsigned long long* dst = packed + offs[layer] + (gate & 3) * dout + 2 * c2;
    atomicMax(dst, ((unsigned long long)sortkey(bx) << 32)
                   | (unsigned long long)(0xFFFFFFFFu - (unsigned int)rx));
    atomicMax(dst + 1, ((unsigned long long)sortkey(by) << 32)
                   | (unsigned long long)(0xFFFFFFFFu - (unsigned int)ry));
}

__global__ __launch_bounds__(256) void convert_fb(const unsigned long long* __restrict__ packed,
                                                  ushort2* __restrict__ pf) {
    int i = blockIdx.x * 256 + threadIdx.x;
    if (i >= 5120) return;
    int l    = (i < 2048) ? 0 : ((i < 4096) ? 1 : 2);
    int half = (l == 2) ? 512 : 1024;
    int r    = i - l * 2048;
    int type = (r >= half) ? 1 : 0;
    int g    = r - type * half;
    int o1   = l * 4096 + 2 * type * half + g;
    int o2   = o1 + half;
    unsigned int i1 = 0xFFFFFFFFu - (unsigned int)(packed[o1] & 0xFFFFFFFFull);
    unsigned int i2 = 0xFFFFFFFFu - (unsigned int)(packed[o2] & 0xFFFFFFFFull);
    pf[i] = make_ushort2((unsigned short)i1, (unsigned short)i2);
}

// ---------------- forward: 4 rows/block, fp16 packed h ----------------------
__device__ __forceinline__ __half2 bc(unsigned int u) { return __builtin_bit_cast(__half2, u); }
__device__ __forceinline__ unsigned int cb(__half2 h) { return __builtin_bit_cast(unsigned int, h); }

__device__ __forceinline__ uint2 gat(const char* hb, unsigned int s) {
    return *(const uint2*)(hb + (s << 3));
}
__device__ __forceinline__ uint2 andg(uint2 a, uint2 b) {
    return make_uint2(cb(__hmul2(bc(a.x), bc(b.x))), cb(__hmul2(bc(a.y), bc(b.y))));
}
__device__ __forceinline__ uint2 org(uint2 a, uint2 b) {
    __half2 one = __float2half2_rn(1.0f);
    __half2 lo = __hsub2(one, __hmul2(__hsub2(one, bc(a.x)), __hsub2(one, bc(b.x))));
    __half2 hi = __hsub2(one, __hmul2(__hsub2(one, bc(a.y)), __hsub2(one, bc(b.y))));
    return make_uint2(cb(lo), cb(hi));
}

__global__ __launch_bounds__(512) void forward_kernel(const float* __restrict__ x,
                                                      const float* __restrict__ lin_w,
                                                      const ushort2* __restrict__ pairs,
                                                      float* __restrict__ out) {
    __shared__ uint2 h[5122];      // slot s = 4 rows of feature s, fp16 packed
    __shared__ float4 red[8];
    const int t  = threadIdx.x;
    const int r0 = blockIdx.x * 4;
    const char* hb = (const char*)h;

    float xa = x[(size_t)(r0 + 0) * 512 + t];
    float xb = x[(size_t)(r0 + 1) * 512 + t];
    float xc = x[(size_t)(r0 + 2) * 512 + t];
    float xd = x[(size_t)(r0 + 3) * 512 + t];
    ushort2 pa0 = pairs[t], pa1 = pairs[512 + t];
    ushort2 po0 = pairs[1024 + t], po1 = pairs[1536 + t];
    h[t]       = make_uint2(cb(__floats2half2_rn(xa, xb)), cb(__floats2half2_rn(xc, xd)));
    h[512 + t] = make_uint2(cb(__floats2half2_rn(1.f - xa, 1.f - xb)),
                            cb(__floats2half2_rn(1.f - xc, 1.f - xd)));
    if (t == 0) {
        unsigned int o = cb(__float2half2_rn(1.0f));
        h[1024] = make_uint2(o, o);
        h[1025] = make_uint2(0u, 0u);
    }
    __syncthreads();

    {
        uint2 a0 = andg(gat(hb, pa0.x), gat(hb, pa0.y));
        uint2 a1 = andg(gat(hb, pa1.x), gat(hb, pa1.y));
        uint2 o0 = org(gat(hb, po0.x), gat(hb, po0.y));
        uint2 o1 = org(gat(hb, po1.x), gat(hb, po1.y));
        h[1026 + t] = a0; h[1538 + t] = a1;
        h[2050 + t] = o0; h[2562 + t] = o1;
    }
    ushort2 qa0 = pairs[2048 + t], qa1 = pairs[2560 + t];
    ushort2 qo0 = pairs[3072 + t], qo1 = pairs[3584 + t];
    __syncthreads();

    {
        uint2 a0 = andg(gat(hb, qa0.x), gat(hb, qa0.y));
        uint2 a1 = andg(gat(hb, qa1.x), gat(hb, qa1.y));
        uint2 o0 = org(gat(hb, qo0.x), gat(hb, qo0.y));
        uint2 o1 = org(gat(hb, qo1.x), gat(hb, qo1.y));
        h[3074 + t] = a0; h[3586 + t] = a1;
        h[4098 + t] = o0; h[4610 + t] = o1;
    }
    ushort2 za = pairs[4096 + t], zo = pairs[4608 + t];
    float wA = lin_w[t], wO = lin_w[512 + t];
    __syncthreads();

    uint2 cg = andg(gat(hb, za.x), gat(hb, za.y));
    uint2 dg = org(gat(hb, zo.x), gat(hb, zo.y));
    float2 cl = __half22float2(bc(cg.x)), ch2 = __half22float2(bc(cg.y));
    float2 dl = __half22float2(bc(dg.x)), dh = __half22float2(bc(dg.y));
    float4 s;
    s.x = wA * cl.x  + wO * dl.x;
    s.y = wA * cl.y  + wO * dl.y;
    s.z = wA * ch2.x + wO * dh.x;
    s.w = wA * ch2.y + wO * dh.y;

    #pragma unroll
    for (int off = 32; off > 0; off >>= 1) {
        s.x += __shfl_down(s.x, off, 64);
        s.y += __shfl_down(s.y, off, 64);
        s.z += __shfl_down(s.z, off, 64);
        s.w += __shfl_down(s.w, off, 64);
    }
    if ((t & 63) == 0) red[t >> 6] = s;
    __syncthreads();
    if (t == 0) {
        float4 tot = red[0];
        #pragma unroll
        for (int i = 1; i < 8; ++i) {
            tot.x += red[i].x; tot.y += red[i].y;
            tot.z += red[i].z; tot.w += red[i].w;
        }
        *(float4*)(out + r0) = tot;
    }
}

extern "C" void kernel_launch(void* const* d_in, const int* in_sizes, int n_in,
                              void* d_out, int out_size, void* d_ws, size_t ws_size,
                              hipStream_t stream) {
    GatePtrs gp;
    for (int l = 0; l < 3; ++l)
        for (int s = 0; s < 4; ++s) {
            gp.w[l * 4 + s] = (const float*)d_in[l * 8 + s];
            gp.g[l * 4 + s] = (const float*)d_in[l * 8 + 4 + s];
        }
    const float* x     = (const float*)d_in[24];
    const float* lin_w = (const float*)d_in[25];
    float* out = (float*)d_out;

    const size_t partBytes = 1714176ull * 8ull;   // 13,713,408
    if (ws_size >= partBytes + 20480) {
        unsigned long long* part = (unsigned long long*)d_ws;
        unsigned short* pf = (unsigned short*)((char*)d_ws + partBytes);
        argmax_part<<<1676, 256, 0, stream>>>(gp, part);
        reduce_pairs2<<<320, 256, 0, stream>>>(part, pf);
        forward_kernel<<<8192, 512, 0, stream>>>(x, lin_w, (const ushort2*)pf, out);
    } else {
        unsigned long long* packed = (unsigned long long*)d_ws;
        ushort2* pf = (ushort2*)((char*)d_ws + 10240 * 8);
        hipMemsetAsync(d_ws, 0, 10240 * 8, stream);
        dim3 ga(2, 81, 12);
        argmax_atomic<<<ga, 256, 0, stream>>>(gp, packed);
        convert_fb<<<20, 256, 0, stream>>>(packed, pf);
        forward_kernel<<<8192, 512, 0, stream>>>(x, lin_w, (const ushort2*)pf, out);
    }
}

// Round 3
// 341.416 us; speedup vs baseline: 1.0106x; 1.0062x over previous
//
#include <hip/hip_runtime.h>
#include <hip/hip_fp16.h>
#include <stdint.h>

// ---------------------------------------------------------------------------
// RuleModel forward. ST-gumbel gate forward == exact one-hot column selector,
// so each h @ gate is a gather with index argmax_i(w[i,j]+g[i,j]).
// Fast path: argmax_part (flat exact grid; inner loop is INLINE-ASM
// global_load_dwordx4 with an 8-row x (w,g) register ring and hand-counted
// s_waitcnt vmcnt(N) -- 16 loads stay in flight per thread; the compiler
// cannot re-serialize opaque asm loads) -> reduce_pairs2 (cooperative,
// coalesced) -> forward (4 rows/block, fp16 h).
// Fallback (small ws): memset -> atomic argmax -> convert -> forward.
// ---------------------------------------------------------------------------

struct GatePtrs {
    const float* w[12];
    const float* g[12];
};

typedef float f32x4 __attribute__((ext_vector_type(4)));

__device__ __forceinline__ unsigned int sortkey(float f) {
    unsigned int u = __float_as_uint(f);
    return u ^ ((u & 0x80000000u) ? 0xFFFFFFFFu : 0x80000000u);
}

// ---------------- fast path: phase A ---------------------------------------
// partial layout (u64): per layer base pbs[l]; entry (slot, chunk, col) at
// pbs[l] + (slot*ch[l] + chunk)*dout[l] + col. chunk = 16 rows.
// value = (sortkey(best) << 32) | best_row.
// Flat grid of exactly-active blocks:
//   L0: blocks [0,260)    = 4 gates x 65 chunks, 256 cols4 each
//   L1: blocks [260,1032) = 4 gates x 193 chunks
//   L2: blocks [1032,1676)= 4 gates x 161 y-slots (2 chunks of 128 cols4)
__global__ __launch_bounds__(256) void argmax_part(GatePtrs gp,
                                                   unsigned long long* __restrict__ part) {
    const int dins[3]  = {1026, 3074, 5122};
    const int chs[3]   = {65, 193, 321};
    const int pbs[3]   = {0, 266240, 1056768};
    int bid = blockIdx.x;
    int layer, slot, chunk, c4, dout;
    if (bid < 260) {
        layer = 0; slot = bid / 65; chunk = bid - slot * 65;
        c4 = threadIdx.x; dout = 1024;
    } else if (bid < 1032) {
        layer = 1; int r = bid - 260; slot = r / 193; chunk = r - slot * 193;
        c4 = threadIdx.x; dout = 1024;
    } else {
        layer = 2; int r = bid - 1032; slot = r / 161; int cb = r - slot * 161;
        int sub = threadIdx.x >> 7; c4 = threadIdx.x & 127; dout = 512;
        chunk = cb * 2 + sub;
        if (chunk >= 321) return;             // odd tail of the pairing
    }
    int gate = layer * 4 + slot;
    int din = dins[layer], ch = chs[layer];
    int s4 = dout >> 2;                       // float4s per row
    int r0 = chunk * 16;
    int n  = min(16, din - r0);               // 16 or 2 (tail chunk)
    const float4* __restrict__ wp = (const float4*)gp.w[gate] + (size_t)r0 * s4 + c4;
    const float4* __restrict__ gq = (const float4*)gp.g[gate] + (size_t)r0 * s4 + c4;
    float bx = -3.4e38f, by = bx, bz = bx, bw = bx;
    int ix = r0, iy = r0, iz = r0, iw = r0;
    if (n == 16) {
        // Inline-asm software pipeline. 8-deep (w,g) register ring; loads are
        // opaque asm so the scheduler can neither sink them to their uses nor
        // shrink the ring. Steady state: 16 dwordx4 loads in flight/thread.
        // Consume of row k waits at vmcnt(14) (rows k+1..k+8 still in
        // flight), never vmcnt(0) until the drain. sched_barrier(0) after
        // each wait pins the dependent VALU below it (rule: compiler hoists
        // register-only ops past inline-asm waitcnt otherwise).
        f32x4 wv[8], gv[8];
        const size_t rs = (size_t)s4;
#define ISSUE(k)                                                               \
        asm volatile("global_load_dwordx4 %0, %1, off"                         \
                     : "=v"(wv[(k) & 7]) : "v"(wp + (size_t)(k) * rs));        \
        asm volatile("global_load_dwordx4 %0, %1, off"                         \
                     : "=v"(gv[(k) & 7]) : "v"(gq + (size_t)(k) * rs));
#define STAGE(k, NW)                                                           \
        asm volatile("s_waitcnt vmcnt(" #NW ")");                              \
        __builtin_amdgcn_sched_barrier(0);                                     \
        {                                                                      \
            const int kk = (k);                                                \
            int i = r0 + kk;                                                   \
            float vx = wv[kk & 7].x + gv[kk & 7].x;                            \
            float vy = wv[kk & 7].y + gv[kk & 7].y;                            \
            float vz = wv[kk & 7].z + gv[kk & 7].z;                            \
            float vw = wv[kk & 7].w + gv[kk & 7].w;                            \
            if (vx > bx) { bx = vx; ix = i; } /* strict > keeps first row */   \
            if (vy > by) { by = vy; iy = i; }                                  \
            if (vz > bz) { bz = vz; iz = i; }                                  \
            if (vw > bw) { bw = vw; iw = i; }                                  \
        }
        ISSUE(0) ISSUE(1) ISSUE(2) ISSUE(3)
        ISSUE(4) ISSUE(5) ISSUE(6) ISSUE(7)          // 16 outstanding
        STAGE(0, 14) ISSUE(8)                        // consume k, refill k+8
        STAGE(1, 14) ISSUE(9)
        STAGE(2, 14) ISSUE(10)
        STAGE(3, 14) ISSUE(11)
        STAGE(4, 14) ISSUE(12)
        STAGE(5, 14) ISSUE(13)
        STAGE(6, 14) ISSUE(14)
        STAGE(7, 14) ISSUE(15)
        STAGE(8, 14)                                 // drain
        STAGE(9, 12)
        STAGE(10, 10)
        STAGE(11, 8)
        STAGE(12, 6)
        STAGE(13, 4)
        STAGE(14, 2)
        STAGE(15, 0)
#undef ISSUE
#undef STAGE
    } else {
        for (int m = 0; m < n; ++m) {
            float4 wv = wp[(size_t)m * s4];
            float4 gv = gq[(size_t)m * s4];
            int i = r0 + m;
            float vx = wv.x + gv.x, vy = wv.y + gv.y;
            float vz = wv.z + gv.z, vw = wv.w + gv.w;
            if (vx > bx) { bx = vx; ix = i; }
            if (vy > by) { by = vy; iy = i; }
            if (vz > bz) { bz = vz; iz = i; }
            if (vw > bw) { bw = vw; iw = i; }
        }
    }
    unsigned long long* dst = part + pbs[layer]
                            + ((size_t)(slot * ch + chunk)) * dout + 4 * c4;
    dst[0] = ((unsigned long long)sortkey(bx) << 32) | (unsigned int)ix;
    dst[1] = ((unsigned long long)sortkey(by) << 32) | (unsigned int)iy;
    dst[2] = ((unsigned long long)sortkey(bz) << 32) | (unsigned int)iz;
    dst[3] = ((unsigned long long)sortkey(bw) << 32) | (unsigned int)iw;
}

// ---------------- fast path: phase B (cooperative reduce) -------------------
// 320 blocks x 256 threads: 32 columns x 8 chunk-lanes. Coalesced reads,
// LDS tree over chunk-lanes. pf[2i+e] = input-e slot index of gate-pair i.
__global__ __launch_bounds__(256) void reduce_pairs2(const unsigned long long* __restrict__ part,
                                                     unsigned short* __restrict__ pf) {
    __shared__ unsigned long long red[256];
    int t = threadIdx.x;
    int k = t >> 5, gi = t & 31;
    int C = blockIdx.x * 32;                  // global col-slot base
    int l, s, g0, half, dout, ch, pb;
    if (C < 4096)      { l = 0; s = C >> 10;          g0 = C & 1023;          half = 1024; dout = 1024; ch = 65;  pb = 0; }
    else if (C < 8192) { l = 1; s = (C - 4096) >> 10; g0 = (C - 4096) & 1023; half = 1024; dout = 1024; ch = 193; pb = 266240; }
    else               { l = 2; s = (C - 8192) >> 9;  g0 = (C - 8192) & 511;  half = 512;  dout = 512;  ch = 321; pb = 1056768; }
    int g = g0 + gi;
    const unsigned long long* __restrict__ p = part + pb + (size_t)(s * ch) * dout + g;
    unsigned long long best = 0;
    for (int c = k; c < ch; c += 8) {
        unsigned long long v = p[(size_t)c * dout];
        if ((unsigned int)(v >> 32) > (unsigned int)(best >> 32)) best = v;
    }
    red[t] = best;
    __syncthreads();
    #pragma unroll
    for (int st = 4; st >= 1; st >>= 1) {
        if (k < st) {
            unsigned long long o = red[t + st * 32];
            if ((unsigned int)(o >> 32) > (unsigned int)(best >> 32)) best = o;
            red[t] = best;
        }
        __syncthreads();
    }
    if (k == 0) {
        int type = s >> 1, e = s & 1;
        int j = 2 * (l * 2048 + type * half + g) + e;
        pf[j] = (unsigned short)best;         // low 16 bits = row index (<5122)
    }
}

// ---------------- fallback: atomic argmax + convert -------------------------
__global__ __launch_bounds__(256) void argmax_atomic(GatePtrs gp,
                                                     unsigned long long* __restrict__ packed) {
    const int dins[3]  = {1026, 3074, 5122};
    const int douts[3] = {1024, 1024, 512};
    const int offs[3]  = {0, 4096, 8192};
    int gate = blockIdx.z, layer = gate >> 2;
    int din = dins[layer], dout = douts[layer];
    int c2 = blockIdx.x * 256 + threadIdx.x;
    int r0 = blockIdx.y * 64;
    if (2 * c2 >= dout || r0 >= din) return;
    int r1 = min(r0 + 64, din);
    const float* __restrict__ w = gp.w[gate];
    const float* __restrict__ g = gp.g[gate];
    float bx = -3.4e38f, by = -3.4e38f;
    int rx = r0, ry = r0;
    #pragma unroll 8
    for (int i = r0; i < r1; ++i) {
        float2 wv = *(const float2*)(w + (size_t)i * dout + 2 * c2);
        float2 gv = *(const float2*)(g + (size_t)i * dout + 2 * c2);
        float vx = wv.x + gv.x, vy = wv.y + gv.y;
        if (vx > bx) { bx = vx; rx = i; }
        if (vy > by) { by = vy; ry = i; }
    }
    unsigned long long* dst = packed + offs[layer] + (gate & 3) * dout + 2 * c2;
    atomicMax(dst, ((unsigned long long)sortkey(bx) << 32)
                   | (unsigned long long)(0xFFFFFFFFu - (unsigned int)rx));
    atomicMax(dst + 1, ((unsigned long long)sortkey(by) << 32)
                   | (unsigned long long)(0xFFFFFFFFu - (unsigned int)ry));
}

__global__ __launch_bounds__(256) void convert_fb(const unsigned long long* __restrict__ packed,
                                                  ushort2* __restrict__ pf) {
    int i = blockIdx.x * 256 + threadIdx.x;
    if (i >= 5120) return;
    int l    = (i < 2048) ? 0 : ((i < 4096) ? 1 : 2);
    int half = (l == 2) ? 512 : 1024;
    int r    = i - l * 2048;
    int type = (r >= half) ? 1 : 0;
    int g    = r - type * half;
    int o1   = l * 4096 + 2 * type * half + g;
    int o2   = o1 + half;
    unsigned int i1 = 0xFFFFFFFFu - (unsigned int)(packed[o1] & 0xFFFFFFFFull);
    unsigned int i2 = 0xFFFFFFFFu - (unsigned int)(packed[o2] & 0xFFFFFFFFull);
    pf[i] = make_ushort2((unsigned short)i1, (unsigned short)i2);
}

// ---------------- forward: 4 rows/block, fp16 packed h ----------------------
__device__ __forceinline__ __half2 bc(unsigned int u) { return __builtin_bit_cast(__half2, u); }
__device__ __forceinline__ unsigned int cb(__half2 h) { return __builtin_bit_cast(unsigned int, h); }

__device__ __forceinline__ uint2 gat(const char* hb, unsigned int s) {
    return *(const uint2*)(hb + (s << 3));
}
__device__ __forceinline__ uint2 andg(uint2 a, uint2 b) {
    return make_uint2(cb(__hmul2(bc(a.x), bc(b.x))), cb(__hmul2(bc(a.y), bc(b.y))));
}
__device__ __forceinline__ uint2 org(uint2 a, uint2 b) {
    __half2 one = __float2half2_rn(1.0f);
    __half2 lo = __hsub2(one, __hmul2(__hsub2(one, bc(a.x)), __hsub2(one, bc(b.x))));
    __half2 hi = __hsub2(one, __hmul2(__hsub2(one, bc(a.y)), __hsub2(one, bc(b.y))));
    return make_uint2(cb(lo), cb(hi));
}

__global__ __launch_bounds__(512) void forward_kernel(const float* __restrict__ x,
                                                      const float* __restrict__ lin_w,
                                                      const ushort2* __restrict__ pairs,
                                                      float* __restrict__ out) {
    __shared__ uint2 h[5122];      // slot s = 4 rows of feature s, fp16 packed
    __shared__ float4 red[8];
    const int t  = threadIdx.x;
    const int r0 = blockIdx.x * 4;
    const char* hb = (const char*)h;

    float xa = x[(size_t)(r0 + 0) * 512 + t];
    float xb = x[(size_t)(r0 + 1) * 512 + t];
    float xc = x[(size_t)(r0 + 2) * 512 + t];
    float xd = x[(size_t)(r0 + 3) * 512 + t];
    ushort2 pa0 = pairs[t], pa1 = pairs[512 + t];
    ushort2 po0 = pairs[1024 + t], po1 = pairs[1536 + t];
    h[t]       = make_uint2(cb(__floats2half2_rn(xa, xb)), cb(__floats2half2_rn(xc, xd)));
    h[512 + t] = make_uint2(cb(__floats2half2_rn(1.f - xa, 1.f - xb)),
                            cb(__floats2half2_rn(1.f - xc, 1.f - xd)));
    if (t == 0) {
        unsigned int o = cb(__float2half2_rn(1.0f));
        h[1024] = make_uint2(o, o);
        h[1025] = make_uint2(0u, 0u);
    }
    __syncthreads();

    {
        uint2 a0 = andg(gat(hb, pa0.x), gat(hb, pa0.y));
        uint2 a1 = andg(gat(hb, pa1.x), gat(hb, pa1.y));
        uint2 o0 = org(gat(hb, po0.x), gat(hb, po0.y));
        uint2 o1 = org(gat(hb, po1.x), gat(hb, po1.y));
        h[1026 + t] = a0; h[1538 + t] = a1;
        h[2050 + t] = o0; h[2562 + t] = o1;
    }
    ushort2 qa0 = pairs[2048 + t], qa1 = pairs[2560 + t];
    ushort2 qo0 = pairs[3072 + t], qo1 = pairs[3584 + t];
    __syncthreads();

    {
        uint2 a0 = andg(gat(hb, qa0.x), gat(hb, qa0.y));
        uint2 a1 = andg(gat(hb, qa1.x), gat(hb, qa1.y));
        uint2 o0 = org(gat(hb, qo0.x), gat(hb, qo0.y));
        uint2 o1 = org(gat(hb, qo1.x), gat(hb, qo1.y));
        h[3074 + t] = a0; h[3586 + t] = a1;
        h[4098 + t] = o0; h[4610 + t] = o1;
    }
    ushort2 za = pairs[4096 + t], zo = pairs[4608 + t];
    float wA = lin_w[t], wO = lin_w[512 + t];
    __syncthreads();

    uint2 cg = andg(gat(hb, za.x), gat(hb, za.y));
    uint2 dg = org(gat(hb, zo.x), gat(hb, zo.y));
    float2 cl = __half22float2(bc(cg.x)), ch2 = __half22float2(bc(cg.y));
    float2 dl = __half22float2(bc(dg.x)), dh = __half22float2(bc(dg.y));
    float4 s;
    s.x = wA * cl.x  + wO * dl.x;
    s.y = wA * cl.y  + wO * dl.y;
    s.z = wA * ch2.x + wO * dh.x;
    s.w = wA * ch2.y + wO * dh.y;

    #pragma unroll
    for (int off = 32; off > 0; off >>= 1) {
        s.x += __shfl_down(s.x, off, 64);
        s.y += __shfl_down(s.y, off, 64);
        s.z += __shfl_down(s.z, off, 64);
        s.w += __shfl_down(s.w, off, 64);
    }
    if ((t & 63) == 0) red[t >> 6] = s;
    __syncthreads();
    if (t == 0) {
        float4 tot = red[0];
        #pragma unroll
        for (int i = 1; i < 8; ++i) {
            tot.x += red[i].x; tot.y += red[i].y;
            tot.z += red[i].z; tot.w += red[i].w;
        }
        *(float4*)(out + r0) = tot;
    }
}

extern "C" void kernel_launch(void* const* d_in, const int* in_sizes, int n_in,
                              void* d_out, int out_size, void* d_ws, size_t ws_size,
                              hipStream_t stream) {
    GatePtrs gp;
    for (int l = 0; l < 3; ++l)
        for (int s = 0; s < 4; ++s) {
            gp.w[l * 4 + s] = (const float*)d_in[l * 8 + s];
            gp.g[l * 4 + s] = (const float*)d_in[l * 8 + 4 + s];
        }
    const float* x     = (const float*)d_in[24];
    const float* lin_w = (const float*)d_in[25];
    float* out = (float*)d_out;

    const size_t partBytes = 1714176ull * 8ull;   // 13,713,408
    if (ws_size >= partBytes + 20480) {
        unsigned long long* part = (unsigned long long*)d_ws;
        unsigned short* pf = (unsigned short*)((char*)d_ws + partBytes);
        argmax_part<<<1676, 256, 0, stream>>>(gp, part);
        reduce_pairs2<<<320, 256, 0, stream>>>(part, pf);
        forward_kernel<<<8192, 512, 0, stream>>>(x, lin_w, (const ushort2*)pf, out);
    } else {
        unsigned long long* packed = (unsigned long long*)d_ws;
        ushort2* pf = (ushort2*)((char*)d_ws + 10240 * 8);
        hipMemsetAsync(d_ws, 0, 10240 * 8, stream);
        dim3 ga(2, 81, 12);
        argmax_atomic<<<ga, 256, 0, stream>>>(gp, packed);
        convert_fb<<<20, 256, 0, stream>>>(packed, pf);
        forward_kernel<<<8192, 512, 0, stream>>>(x, lin_w, (const ushort2*)pf, out);
    }
}